// Round 1
// baseline (2267.860 us; speedup 1.0000x reference)
//
#include <hip/hip_runtime.h>

#define BATCH  200
#define IN_DIM 2312
#define HD1    800
#define HD2    10
#define TWIN   8

// ---------------------------------------------------------------------------
// K0a: input [B][C][H][W][T] -> xall [T][B][IN_DIM]  (i = c*1156 + h*34 + w)
//   in[(b*IN_DIM + i)*8 + t]  ->  xall[(t*BATCH + b)*IN_DIM + i]
// Block: 512 threads, handles one b and 64 consecutive i for all 8 t.
// ---------------------------------------------------------------------------
__global__ __launch_bounds__(512) void k_transpose_in(const float* __restrict__ in,
                                                      float* __restrict__ xall) {
  __shared__ float lds[512];
  int b  = blockIdx.y;
  int i0 = blockIdx.x * 64;
  int tid = threadIdx.x;
  int il = tid >> 3, t = tid & 7;       // read side: contiguous 2048B chunk
  int i = i0 + il;
  lds[tid] = (i < IN_DIM) ? in[((size_t)(b * IN_DIM + i) << 3) + t] : 0.f;
  __syncthreads();
  int t2 = tid >> 6, il2 = tid & 63;    // write side: 64 consecutive i per t
  int i2 = i0 + il2;
  if (i2 < IN_DIM)
    xall[((size_t)(t2 * BATCH + b)) * IN_DIM + i2] = lds[il2 * 8 + t2];
}

// ---------------------------------------------------------------------------
// K0b: init state buffers, copy hebb inputs into the output regions
// ---------------------------------------------------------------------------
__global__ __launch_bounds__(256) void k_init(const float* __restrict__ h1in,
                                              const float* __restrict__ h2in,
                                              float* __restrict__ hebb1,
                                              float* __restrict__ hebb2,
                                              float* __restrict__ mem1,
                                              float* __restrict__ spike1,
                                              float* __restrict__ mem2,
                                              float* __restrict__ spike2) {
  int stride = gridDim.x * blockDim.x;
  int n1 = IN_DIM * HD1;
  for (int k = blockIdx.x * blockDim.x + threadIdx.x; k < n1; k += stride) {
    hebb1[k] = h1in[k];
    if (k < HD1 * HD2)  hebb2[k] = h2in[k];
    if (k < BATCH * HD1) { mem1[k] = 0.f; spike1[k] = 0.f; }
    if (k < BATCH * HD2) { mem2[k] = 0.f; spike2[k] = 0.f; }
  }
}

// ---------------------------------------------------------------------------
// K1: Wc1[i][j] = W1[j][i] + alpha1 * hebb1[i][j]   (i<2312, j<800)
// Tiled transpose so both reads and the write are coalesced.
// ---------------------------------------------------------------------------
__global__ __launch_bounds__(256) void k_prep_wc1(const float* __restrict__ W1,
                                                  const float* __restrict__ hebb1,
                                                  const float* __restrict__ alpha1,
                                                  float* __restrict__ Wc1) {
  __shared__ float lds[32][33];
  float al = alpha1[0];
  int i0 = blockIdx.x * 32;   // IN_DIM tiles (73)
  int j0 = blockIdx.y * 32;   // HD1 tiles (25)
  int tx = threadIdx.x, ty = threadIdx.y;   // 32 x 8
#pragma unroll
  for (int q = 0; q < 4; q++) {
    int j = j0 + ty + q * 8, i = i0 + tx;
    lds[ty + q * 8][tx] = (j < HD1 && i < IN_DIM) ? W1[(size_t)j * IN_DIM + i] : 0.f;
  }
  __syncthreads();
#pragma unroll
  for (int q = 0; q < 4; q++) {
    int i = i0 + ty + q * 8, j = j0 + tx;
    if (i < IN_DIM)
      Wc1[(size_t)i * HD1 + j] = lds[tx][ty + q * 8] + al * hebb1[(size_t)i * HD1 + j];
  }
}

// ---------------------------------------------------------------------------
// K2: state1 = xt @ Wc1 + b1, fused membrane update epilogue.
//   M=200 (batch), N=800, K=2312.  32x32 tile, 256 thr, 2x2 per thread.
//   epilogue: mem = mem*(1-spike_old)*0.25 + state; spike = mem-0.4 > 0;
//             post = mem/0.4 - eta1
// ---------------------------------------------------------------------------
__global__ __launch_bounds__(256) void k_state1(const float* __restrict__ xt,
                                                const float* __restrict__ Wc1,
                                                const float* __restrict__ b1,
                                                const float* __restrict__ eta1,
                                                float* __restrict__ mem1,
                                                float* __restrict__ spike1,
                                                float* __restrict__ post1) {
  __shared__ float As[32][33];   // As[m][k]
  __shared__ float Bs[32][33];   // Bs[k][n]
  int m0 = blockIdx.x * 32;
  int n0 = blockIdx.y * 32;
  int tid = threadIdx.x;
  int tx = tid & 15, ty = tid >> 4;
  float a00 = 0.f, a01 = 0.f, a10 = 0.f, a11 = 0.f;
  for (int k0 = 0; k0 < IN_DIM; k0 += 32) {
#pragma unroll
    for (int q = 0; q < 4; q++) {
      int e = tid + 256 * q;
      int r = e >> 5, c = e & 31;
      int m = m0 + r, k = k0 + c;
      As[r][c] = (m < BATCH && k < IN_DIM) ? xt[(size_t)m * IN_DIM + k] : 0.f;
      int kb = k0 + r;
      Bs[r][c] = (kb < IN_DIM) ? Wc1[(size_t)kb * HD1 + n0 + c] : 0.f;
    }
    __syncthreads();
#pragma unroll
    for (int kk = 0; kk < 32; kk++) {
      float x0 = As[ty * 2][kk],     x1 = As[ty * 2 + 1][kk];
      float w0 = Bs[kk][tx * 2],     w1 = Bs[kk][tx * 2 + 1];
      a00 += x0 * w0; a01 += x0 * w1; a10 += x1 * w0; a11 += x1 * w1;
    }
    __syncthreads();
  }
  float accs[2][2] = {{a00, a01}, {a10, a11}};
#pragma unroll
  for (int dm = 0; dm < 2; dm++) {
    int m = m0 + ty * 2 + dm;
    if (m >= BATCH) continue;
#pragma unroll
    for (int dn = 0; dn < 2; dn++) {
      int n = n0 + tx * 2 + dn;
      float state = accs[dm][dn] + b1[n];
      int idx = m * HD1 + n;
      float mo = mem1[idx], so = spike1[idx];
      float mn = mo * (1.f - so) * 0.25f + state;
      mem1[idx]   = mn;
      spike1[idx] = (mn - 0.4f > 0.f) ? 1.f : 0.f;
      post1[idx]  = mn / 0.4f - eta1[n];
    }
  }
}

// ---------------------------------------------------------------------------
// K3: G = xtT @ post1  (M=2312(i), N=800(j), K=200(b)), fused hebb1 update:
//   hebb1 = clip(0.99*hebb1 - max(beta1[i],0)*G/200, -5, 5)
// ---------------------------------------------------------------------------
__global__ __launch_bounds__(256) void k_hebb1(const float* __restrict__ xt,
                                               const float* __restrict__ post1,
                                               const float* __restrict__ beta1,
                                               float* __restrict__ hebb1) {
  __shared__ float As[32][33];   // As[b][i]
  __shared__ float Bs[32][33];   // Bs[b][j]
  int i0 = blockIdx.x * 32;
  int j0 = blockIdx.y * 32;
  int tid = threadIdx.x;
  int tx = tid & 15, ty = tid >> 4;
  float a00 = 0.f, a01 = 0.f, a10 = 0.f, a11 = 0.f;
  for (int k0 = 0; k0 < BATCH; k0 += 32) {
#pragma unroll
    for (int q = 0; q < 4; q++) {
      int e = tid + 256 * q;
      int r = e >> 5, c = e & 31;       // r = b offset, c = col
      int bb = k0 + r;
      int i = i0 + c;
      As[r][c] = (bb < BATCH && i < IN_DIM) ? xt[(size_t)bb * IN_DIM + i] : 0.f;
      Bs[r][c] = (bb < BATCH) ? post1[bb * HD1 + j0 + c] : 0.f;
    }
    __syncthreads();
#pragma unroll
    for (int kk = 0; kk < 32; kk++) {
      float x0 = As[kk][ty * 2], x1 = As[kk][ty * 2 + 1];
      float p0 = Bs[kk][tx * 2], p1 = Bs[kk][tx * 2 + 1];
      a00 += x0 * p0; a01 += x0 * p1; a10 += x1 * p0; a11 += x1 * p1;
    }
    __syncthreads();
  }
  float accs[2][2] = {{a00, a01}, {a10, a11}};
#pragma unroll
  for (int dm = 0; dm < 2; dm++) {
    int i = i0 + ty * 2 + dm;
    if (i >= IN_DIM) continue;
    float bc = fmaxf(beta1[i], 0.f);
#pragma unroll
    for (int dn = 0; dn < 2; dn++) {
      int j = j0 + tx * 2 + dn;
      size_t idx = (size_t)i * HD1 + j;
      float h = 0.99f * hebb1[idx] - bc * accs[dm][dn] / 200.f;
      hebb1[idx] = fminf(fmaxf(h, -5.f), 5.f);
    }
  }
}

// ---------------------------------------------------------------------------
// K4: layer-2 state + membrane update. One wave per (b, j) output; K=800 dot.
//   Folds Wc2 = W2^T + alpha2*hebb2 on the fly. Also writes outs = mem/0.4.
// ---------------------------------------------------------------------------
__global__ __launch_bounds__(256) void k_layer2_state(const float* __restrict__ spike1,
                                                      const float* __restrict__ W2,
                                                      const float* __restrict__ b2,
                                                      const float* __restrict__ hebb2,
                                                      const float* __restrict__ alpha2,
                                                      const float* __restrict__ eta2,
                                                      float* __restrict__ mem2,
                                                      float* __restrict__ spike2,
                                                      float* __restrict__ post2,
                                                      float* __restrict__ outs) {
  int wid  = (int)((blockIdx.x * blockDim.x + threadIdx.x) >> 6);
  int lane = threadIdx.x & 63;
  if (wid >= BATCH * HD2) return;
  int b = wid / HD2, j = wid % HD2;
  float al = alpha2[0];
  float acc = 0.f;
  for (int i = lane; i < HD1; i += 64)
    acc += spike1[b * HD1 + i] * (W2[j * HD1 + i] + al * hebb2[i * HD2 + j]);
#pragma unroll
  for (int off = 32; off > 0; off >>= 1) acc += __shfl_down(acc, off, 64);
  if (lane == 0) {
    float state = acc + b2[j];
    int idx = b * HD2 + j;
    float mo = mem2[idx], so = spike2[idx];
    float mn = mo * (1.f - so) * 0.25f + state;
    mem2[idx]   = mn;
    spike2[idx] = (mn - 0.4f > 0.f) ? 1.f : 0.f;
    post2[idx]  = mn / 0.4f - eta2[j];
    outs[idx]   = mn / 0.4f;   // last timestep's write is the final output
  }
}

// ---------------------------------------------------------------------------
// K5: hebb2 update. One thread per (i, j), K=200.
//   idx = j*800 + i so consecutive lanes read consecutive spike1[b][i].
// ---------------------------------------------------------------------------
__global__ __launch_bounds__(256) void k_hebb2(const float* __restrict__ spike1,
                                               const float* __restrict__ post2,
                                               const float* __restrict__ beta2,
                                               float* __restrict__ hebb2) {
  int idx = blockIdx.x * blockDim.x + threadIdx.x;
  if (idx >= HD1 * HD2) return;
  int i = idx % HD1, j = idx / HD1;
  float acc = 0.f;
  for (int b = 0; b < BATCH; b++)
    acc += spike1[b * HD1 + i] * post2[b * HD2 + j];
  float bc = fmaxf(beta2[i], 0.f);
  float h = 0.99f * hebb2[i * HD2 + j] - bc * acc / 200.f;
  hebb2[i * HD2 + j] = fminf(fmaxf(h, -5.f), 5.f);
}

// ---------------------------------------------------------------------------
extern "C" void kernel_launch(void* const* d_in, const int* in_sizes, int n_in,
                              void* d_out, int out_size, void* d_ws, size_t ws_size,
                              hipStream_t stream) {
  const float* input    = (const float*)d_in[0];
  const float* hebb1_in = (const float*)d_in[1];
  const float* hebb2_in = (const float*)d_in[2];
  const float* W1       = (const float*)d_in[3];
  const float* b1       = (const float*)d_in[4];
  const float* W2       = (const float*)d_in[5];
  const float* b2       = (const float*)d_in[6];
  const float* alpha1   = (const float*)d_in[7];
  const float* alpha2   = (const float*)d_in[8];
  const float* beta1    = (const float*)d_in[9];
  const float* beta2    = (const float*)d_in[10];
  const float* eta1     = (const float*)d_in[11];
  const float* eta2     = (const float*)d_in[12];

  float* out   = (float*)d_out;
  float* outs  = out;                               // [200][10]
  float* hebb1 = out + BATCH * HD2;                 // [2312][800]
  float* hebb2 = hebb1 + (size_t)IN_DIM * HD1;      // [800][10]

  float* ws     = (float*)d_ws;
  float* xall   = ws;                                        // 8*200*2312
  float* Wc1    = xall + (size_t)TWIN * BATCH * IN_DIM;      // 2312*800
  float* mem1   = Wc1 + (size_t)IN_DIM * HD1;                // 200*800
  float* spike1 = mem1 + BATCH * HD1;
  float* post1  = spike1 + BATCH * HD1;
  float* mem2   = post1 + BATCH * HD1;                       // 200*10
  float* spike2 = mem2 + BATCH * HD2;
  float* post2  = spike2 + BATCH * HD2;

  k_transpose_in<<<dim3((IN_DIM + 63) / 64, BATCH), 512, 0, stream>>>(input, xall);
  k_init<<<1024, 256, 0, stream>>>(hebb1_in, hebb2_in, hebb1, hebb2,
                                   mem1, spike1, mem2, spike2);

  for (int t = 0; t < TWIN; t++) {
    const float* xt = xall + (size_t)t * BATCH * IN_DIM;
    k_prep_wc1<<<dim3(73, 25), dim3(32, 8), 0, stream>>>(W1, hebb1, alpha1, Wc1);
    k_state1<<<dim3(7, 25), 256, 0, stream>>>(xt, Wc1, b1, eta1, mem1, spike1, post1);
    k_hebb1<<<dim3(73, 25), 256, 0, stream>>>(xt, post1, beta1, hebb1);
    k_layer2_state<<<dim3((BATCH * HD2 * 64 + 255) / 256), 256, 0, stream>>>(
        spike1, W2, b2, hebb2, alpha2, eta2, mem2, spike2, post2, outs);
    k_hebb2<<<dim3((HD1 * HD2 + 255) / 256), 256, 0, stream>>>(spike1, post2, beta2, hebb2);
  }
}

// Round 2
// 640.877 us; speedup vs baseline: 3.5387x; 3.5387x over previous
//
#include <hip/hip_runtime.h>

#define BATCH  200
#define IN_DIM 2312
#define HD1    800
#define HD2    10
#define TWIN   8
#define NSPLIT 8
#define KCH    304   // split-K chunk (multiple of 16); last chunk = 2312-7*304 = 184

// ---------------------------------------------------------------------------
// K0a: input [B][C][H][W][T] -> xall [T][B][IN_DIM]
// ---------------------------------------------------------------------------
__global__ __launch_bounds__(512) void k_transpose_in(const float* __restrict__ in,
                                                      float* __restrict__ xall) {
  __shared__ float lds[512];
  int b  = blockIdx.y;
  int i0 = blockIdx.x * 64;
  int tid = threadIdx.x;
  int il = tid >> 3, t = tid & 7;
  int i = i0 + il;
  lds[tid] = (i < IN_DIM) ? in[((size_t)(b * IN_DIM + i) << 3) + t] : 0.f;
  __syncthreads();
  int t2 = tid >> 6, il2 = tid & 63;
  int i2 = i0 + il2;
  if (i2 < IN_DIM)
    xall[((size_t)(t2 * BATCH + b)) * IN_DIM + i2] = lds[il2 * 8 + t2];
}

// ---------------------------------------------------------------------------
// K0b: init states, copy hebb inputs into output regions
// ---------------------------------------------------------------------------
__global__ __launch_bounds__(256) void k_init(const float* __restrict__ h1in,
                                              const float* __restrict__ h2in,
                                              float* __restrict__ hebb1,
                                              float* __restrict__ hebb2,
                                              float* __restrict__ mem1,
                                              float* __restrict__ spike1,
                                              float* __restrict__ mem2,
                                              float* __restrict__ spike2) {
  int stride = gridDim.x * blockDim.x;
  int n1 = IN_DIM * HD1;
  for (int k = blockIdx.x * blockDim.x + threadIdx.x; k < n1; k += stride) {
    hebb1[k] = h1in[k];
    if (k < HD1 * HD2)  hebb2[k] = h2in[k];
    if (k < BATCH * HD1) { mem1[k] = 0.f; spike1[k] = 0.f; }
    if (k < BATCH * HD2) { mem2[k] = 0.f; spike2[k] = 0.f; }
  }
}

// ---------------------------------------------------------------------------
// K1: Wc1[i][j] = W1[j][i] + alpha1 * hebb1[i][j]
// ---------------------------------------------------------------------------
__global__ __launch_bounds__(256) void k_prep_wc1(const float* __restrict__ W1,
                                                  const float* __restrict__ hebb1,
                                                  const float* __restrict__ alpha1,
                                                  float* __restrict__ Wc1) {
  __shared__ float lds[32][33];
  float al = alpha1[0];
  int i0 = blockIdx.x * 32;
  int j0 = blockIdx.y * 32;
  int tx = threadIdx.x, ty = threadIdx.y;   // 32 x 8
#pragma unroll
  for (int q = 0; q < 4; q++) {
    int j = j0 + ty + q * 8, i = i0 + tx;
    lds[ty + q * 8][tx] = (j < HD1 && i < IN_DIM) ? W1[(size_t)j * IN_DIM + i] : 0.f;
  }
  __syncthreads();
#pragma unroll
  for (int q = 0; q < 4; q++) {
    int i = i0 + ty + q * 8, j = j0 + tx;
    if (i < IN_DIM)
      Wc1[(size_t)i * HD1 + j] = lds[tx][ty + q * 8] + al * hebb1[(size_t)i * HD1 + j];
  }
}

// ---------------------------------------------------------------------------
// K2: split-K GEMM  part[s] = xt[, kchunk] @ Wc1[kchunk, ]
//   M=200 N=800 K=2312. 64x64 tile, 256 thr, 4x4/thread, BK=16, 8 K-chunks.
// ---------------------------------------------------------------------------
__global__ __launch_bounds__(256) void k_state_gemm(const float* __restrict__ xt,
                                                    const float* __restrict__ Wc1,
                                                    float* __restrict__ part) {
  __shared__ __align__(16) float As[16][68];   // [k][m]
  __shared__ __align__(16) float Bs[16][68];   // [k][n]
  int m0 = blockIdx.x * 64;
  int n0 = blockIdx.y * 64;
  int s  = blockIdx.z;
  int kstart = s * KCH;
  int kend   = (kstart + KCH < IN_DIM) ? kstart + KCH : IN_DIM;
  int tid = threadIdx.x;
  int tx = tid & 15, ty = tid >> 4;
  int a_m = tid >> 2;            // 0..63
  int a_k = (tid & 3) * 4;       // 0,4,8,12
  int b_k = tid >> 4;            // 0..15
  int b_n = (tid & 15) * 4;      // 0..60
  float acc[4][4] = {};
  for (int k0 = kstart; k0 < kend; k0 += 16) {
    float4 av = make_float4(0.f, 0.f, 0.f, 0.f);
    if (m0 + a_m < BATCH && k0 + a_k < kend)
      av = *(const float4*)&xt[(size_t)(m0 + a_m) * IN_DIM + k0 + a_k];
    As[a_k + 0][a_m] = av.x;
    As[a_k + 1][a_m] = av.y;
    As[a_k + 2][a_m] = av.z;
    As[a_k + 3][a_m] = av.w;
    float4 bv = make_float4(0.f, 0.f, 0.f, 0.f);
    if (k0 + b_k < kend && n0 + b_n < HD1)
      bv = *(const float4*)&Wc1[(size_t)(k0 + b_k) * HD1 + n0 + b_n];
    *(float4*)&Bs[b_k][b_n] = bv;
    __syncthreads();
#pragma unroll
    for (int kk = 0; kk < 16; kk++) {
      float4 a = *(const float4*)&As[kk][ty * 4];
      float4 b = *(const float4*)&Bs[kk][tx * 4];
      acc[0][0] += a.x * b.x; acc[0][1] += a.x * b.y; acc[0][2] += a.x * b.z; acc[0][3] += a.x * b.w;
      acc[1][0] += a.y * b.x; acc[1][1] += a.y * b.y; acc[1][2] += a.y * b.z; acc[1][3] += a.y * b.w;
      acc[2][0] += a.z * b.x; acc[2][1] += a.z * b.y; acc[2][2] += a.z * b.z; acc[2][3] += a.z * b.w;
      acc[3][0] += a.w * b.x; acc[3][1] += a.w * b.y; acc[3][2] += a.w * b.z; acc[3][3] += a.w * b.w;
    }
    __syncthreads();
  }
  int n_base = n0 + tx * 4;
  if (n_base < HD1) {
    float* pp = part + (size_t)s * BATCH * HD1;
#pragma unroll
    for (int dm = 0; dm < 4; dm++) {
      int m = m0 + ty * 4 + dm;
      if (m < BATCH)
        *(float4*)&pp[(size_t)m * HD1 + n_base] =
            make_float4(acc[dm][0], acc[dm][1], acc[dm][2], acc[dm][3]);
    }
  }
}

// ---------------------------------------------------------------------------
// K2b: reduce partials (fixed order -> deterministic) + membrane epilogue
// ---------------------------------------------------------------------------
__global__ __launch_bounds__(256) void k_state_epi(const float* __restrict__ part,
                                                   const float* __restrict__ b1,
                                                   const float* __restrict__ eta1,
                                                   float* __restrict__ mem1,
                                                   float* __restrict__ spike1,
                                                   float* __restrict__ post1) {
  int g = blockIdx.x * blockDim.x + threadIdx.x;
  if (g >= BATCH * (HD1 / 4)) return;
  int m  = g / (HD1 / 4);
  int n4 = (g % (HD1 / 4)) * 4;
  size_t idx = (size_t)m * HD1 + n4;
  float4 sum = *(const float4*)&part[idx];
#pragma unroll
  for (int s = 1; s < NSPLIT; s++) {
    float4 p = *(const float4*)&part[(size_t)s * BATCH * HD1 + idx];
    sum.x += p.x; sum.y += p.y; sum.z += p.z; sum.w += p.w;
  }
  float4 bb = *(const float4*)&b1[n4];
  float4 ee = *(const float4*)&eta1[n4];
  float4 mo = *(const float4*)&mem1[idx];
  float4 so = *(const float4*)&spike1[idx];
  float st[4] = {sum.x + bb.x, sum.y + bb.y, sum.z + bb.z, sum.w + bb.w};
  float mof[4] = {mo.x, mo.y, mo.z, mo.w};
  float sof[4] = {so.x, so.y, so.z, so.w};
  float eef[4] = {ee.x, ee.y, ee.z, ee.w};
  float mn[4], sp[4], po[4];
#pragma unroll
  for (int q = 0; q < 4; q++) {
    mn[q] = mof[q] * (1.f - sof[q]) * 0.25f + st[q];
    sp[q] = (mn[q] - 0.4f > 0.f) ? 1.f : 0.f;
    po[q] = mn[q] / 0.4f - eef[q];
  }
  *(float4*)&mem1[idx]   = make_float4(mn[0], mn[1], mn[2], mn[3]);
  *(float4*)&spike1[idx] = make_float4(sp[0], sp[1], sp[2], sp[3]);
  *(float4*)&post1[idx]  = make_float4(po[0], po[1], po[2], po[3]);
}

// ---------------------------------------------------------------------------
// K3: hebb1 = clip(0.99*hebb1 - max(beta1[i],0) * (xt^T @ post1)/200, -5, 5)
//   M=2312(i) N=800(j) K=200(b). 64x64 tile, 4x4/thread, BK=16.
// ---------------------------------------------------------------------------
__global__ __launch_bounds__(256) void k_hebb1(const float* __restrict__ xt,
                                               const float* __restrict__ post1,
                                               const float* __restrict__ beta1,
                                               float* __restrict__ hebb1) {
  __shared__ __align__(16) float As[16][68];   // [b][i]
  __shared__ __align__(16) float Bs[16][68];   // [b][j]
  int i0 = blockIdx.x * 64;
  int j0 = blockIdx.y * 64;
  int tid = threadIdx.x;
  int tx = tid & 15, ty = tid >> 4;
  int l_b = tid >> 4;            // 0..15
  int l_c = (tid & 15) * 4;      // 0..60
  float acc[4][4] = {};
  for (int b0 = 0; b0 < BATCH; b0 += 16) {
    float4 av = make_float4(0.f, 0.f, 0.f, 0.f);
    if (b0 + l_b < BATCH && i0 + l_c < IN_DIM)
      av = *(const float4*)&xt[(size_t)(b0 + l_b) * IN_DIM + i0 + l_c];
    *(float4*)&As[l_b][l_c] = av;
    float4 bv = make_float4(0.f, 0.f, 0.f, 0.f);
    if (b0 + l_b < BATCH && j0 + l_c < HD1)
      bv = *(const float4*)&post1[(size_t)(b0 + l_b) * HD1 + j0 + l_c];
    *(float4*)&Bs[l_b][l_c] = bv;
    __syncthreads();
#pragma unroll
    for (int kk = 0; kk < 16; kk++) {
      float4 a = *(const float4*)&As[kk][ty * 4];
      float4 b = *(const float4*)&Bs[kk][tx * 4];
      acc[0][0] += a.x * b.x; acc[0][1] += a.x * b.y; acc[0][2] += a.x * b.z; acc[0][3] += a.x * b.w;
      acc[1][0] += a.y * b.x; acc[1][1] += a.y * b.y; acc[1][2] += a.y * b.z; acc[1][3] += a.y * b.w;
      acc[2][0] += a.z * b.x; acc[2][1] += a.z * b.y; acc[2][2] += a.z * b.z; acc[2][3] += a.z * b.w;
      acc[3][0] += a.w * b.x; acc[3][1] += a.w * b.y; acc[3][2] += a.w * b.z; acc[3][3] += a.w * b.w;
    }
    __syncthreads();
  }
  int j_base = j0 + tx * 4;
  if (j_base < HD1) {
#pragma unroll
    for (int dm = 0; dm < 4; dm++) {
      int i = i0 + ty * 4 + dm;
      if (i >= IN_DIM) continue;
      float bc = fmaxf(beta1[i], 0.f);
      size_t idx = (size_t)i * HD1 + j_base;
      float4 h = *(const float4*)&hebb1[idx];
      float hv[4] = {h.x, h.y, h.z, h.w};
#pragma unroll
      for (int dn = 0; dn < 4; dn++) {
        float v = 0.99f * hv[dn] - bc * acc[dm][dn] * (1.f / 200.f);
        hv[dn] = fminf(fmaxf(v, -5.f), 5.f);
      }
      *(float4*)&hebb1[idx] = make_float4(hv[0], hv[1], hv[2], hv[3]);
    }
  }
}

// ---------------------------------------------------------------------------
// K4: layer-2 state + membrane update (wave per (b,j), K=800 dot)
// ---------------------------------------------------------------------------
__global__ __launch_bounds__(256) void k_layer2_state(const float* __restrict__ spike1,
                                                      const float* __restrict__ W2,
                                                      const float* __restrict__ b2,
                                                      const float* __restrict__ hebb2,
                                                      const float* __restrict__ alpha2,
                                                      const float* __restrict__ eta2,
                                                      float* __restrict__ mem2,
                                                      float* __restrict__ spike2,
                                                      float* __restrict__ post2,
                                                      float* __restrict__ outs) {
  int wid  = (int)((blockIdx.x * blockDim.x + threadIdx.x) >> 6);
  int lane = threadIdx.x & 63;
  if (wid >= BATCH * HD2) return;
  int b = wid / HD2, j = wid % HD2;
  float al = alpha2[0];
  float acc = 0.f;
  for (int i = lane; i < HD1; i += 64)
    acc += spike1[b * HD1 + i] * (W2[j * HD1 + i] + al * hebb2[i * HD2 + j]);
#pragma unroll
  for (int off = 32; off > 0; off >>= 1) acc += __shfl_down(acc, off, 64);
  if (lane == 0) {
    float state = acc + b2[j];
    int idx = b * HD2 + j;
    float mo = mem2[idx], so = spike2[idx];
    float mn = mo * (1.f - so) * 0.25f + state;
    mem2[idx]   = mn;
    spike2[idx] = (mn - 0.4f > 0.f) ? 1.f : 0.f;
    post2[idx]  = mn / 0.4f - eta2[j];
    outs[idx]   = mn / 0.4f;
  }
}

// ---------------------------------------------------------------------------
// K5: hebb2 update (thread per (i,j), K=200)
// ---------------------------------------------------------------------------
__global__ __launch_bounds__(256) void k_hebb2(const float* __restrict__ spike1,
                                               const float* __restrict__ post2,
                                               const float* __restrict__ beta2,
                                               float* __restrict__ hebb2) {
  int idx = blockIdx.x * blockDim.x + threadIdx.x;
  if (idx >= HD1 * HD2) return;
  int i = idx % HD1, j = idx / HD1;
  float acc = 0.f;
  for (int b = 0; b < BATCH; b++)
    acc += spike1[b * HD1 + i] * post2[b * HD2 + j];
  float bc = fmaxf(beta2[i], 0.f);
  float h = 0.99f * hebb2[i * HD2 + j] - bc * acc * (1.f / 200.f);
  hebb2[i * HD2 + j] = fminf(fmaxf(h, -5.f), 5.f);
}

// ---------------------------------------------------------------------------
extern "C" void kernel_launch(void* const* d_in, const int* in_sizes, int n_in,
                              void* d_out, int out_size, void* d_ws, size_t ws_size,
                              hipStream_t stream) {
  const float* input    = (const float*)d_in[0];
  const float* hebb1_in = (const float*)d_in[1];
  const float* hebb2_in = (const float*)d_in[2];
  const float* W1       = (const float*)d_in[3];
  const float* b1       = (const float*)d_in[4];
  const float* W2       = (const float*)d_in[5];
  const float* b2       = (const float*)d_in[6];
  const float* alpha1   = (const float*)d_in[7];
  const float* alpha2   = (const float*)d_in[8];
  const float* beta1    = (const float*)d_in[9];
  const float* beta2    = (const float*)d_in[10];
  const float* eta1     = (const float*)d_in[11];
  const float* eta2     = (const float*)d_in[12];

  float* out   = (float*)d_out;
  float* outs  = out;
  float* hebb1 = out + BATCH * HD2;
  float* hebb2 = hebb1 + (size_t)IN_DIM * HD1;

  float* ws     = (float*)d_ws;
  float* xall   = ws;                                        // 8*200*2312
  float* Wc1    = xall + (size_t)TWIN * BATCH * IN_DIM;      // 2312*800
  float* part   = Wc1 + (size_t)IN_DIM * HD1;                // 8*200*800
  float* mem1   = part + (size_t)NSPLIT * BATCH * HD1;       // 200*800
  float* spike1 = mem1 + BATCH * HD1;
  float* post1  = spike1 + BATCH * HD1;
  float* mem2   = post1 + BATCH * HD1;                       // 200*10
  float* spike2 = mem2 + BATCH * HD2;
  float* post2  = spike2 + BATCH * HD2;

  k_transpose_in<<<dim3((IN_DIM + 63) / 64, BATCH), 512, 0, stream>>>(input, xall);
  k_init<<<1024, 256, 0, stream>>>(hebb1_in, hebb2_in, hebb1, hebb2,
                                   mem1, spike1, mem2, spike2);

  for (int t = 0; t < TWIN; t++) {
    const float* xt = xall + (size_t)t * BATCH * IN_DIM;
    k_prep_wc1<<<dim3(73, 25), dim3(32, 8), 0, stream>>>(W1, hebb1, alpha1, Wc1);
    k_state_gemm<<<dim3(4, 13, NSPLIT), 256, 0, stream>>>(xt, Wc1, part);
    k_state_epi<<<dim3((BATCH * (HD1 / 4) + 255) / 256), 256, 0, stream>>>(
        part, b1, eta1, mem1, spike1, post1);
    k_hebb1<<<dim3(37, 13), 256, 0, stream>>>(xt, post1, beta1, hebb1);
    k_layer2_state<<<dim3((BATCH * HD2 * 64 + 255) / 256), 256, 0, stream>>>(
        spike1, W2, b2, hebb2, alpha2, eta2, mem2, spike2, post2, outs);
    k_hebb2<<<dim3((HD1 * HD2 + 255) / 256), 256, 0, stream>>>(spike1, post2, beta2, hebb2);
  }
}